// Round 9
// baseline (2316.672 us; speedup 1.0000x reference)
//
#include <hip/hip_runtime.h>

#define HDIM 64
#define BATCH 256
#define TLEN 2048
#define CH 16      // layer-2 streaming chunk (steps)
#define GTS 32     // pre-GEMM t-tile

typedef float v2f __attribute__((ext_vector_type(2)));

__device__ __forceinline__ float rcp_fast(float x) { return __builtin_amdgcn_rcpf(x); }
__device__ __forceinline__ float sigmoid_fast(float x) { return rcp_fast(1.0f + __expf(-x)); }
__device__ __forceinline__ float tanh_fast(float x)    { return 1.0f - 2.0f * rcp_fast(1.0f + __expf(2.0f * x)); }

__device__ __forceinline__ float dpp_xor1_add(float x) {
    int v = __builtin_amdgcn_update_dpp(0, __float_as_int(x), 0xB1, 0xF, 0xF, true);
    return x + __int_as_float(v);
}
__device__ __forceinline__ float dpp_xor2_add(float x) {
    int v = __builtin_amdgcn_update_dpp(0, __float_as_int(x), 0x4E, 0xF, 0xF, true);
    return x + __int_as_float(v);
}
__device__ __forceinline__ float swz_xor4_add(float x) {
    int v = __builtin_amdgcn_ds_swizzle(__float_as_int(x), 0x101F);
    return x + __int_as_float(v);
}

__device__ __forceinline__ void pk2(v2f& acc, float ax, float ay, float bx, float by) {
    v2f a = {ax, ay}, b = {bx, by};
    acc = __builtin_elementwise_fma(a, b, acc);
}
__device__ __forceinline__ void pk4(v2f& acc, const float4 a, const float4 b) {
    pk2(acc, a.x, a.y, b.x, b.y);
    pk2(acc, a.z, a.w, b.z, b.w);
}

// Loop-carried register pin: empty non-volatile asm with "+v" makes the value
// an opaque loop-carried VGPR dependency -> allocator's cheapest solution is
// keeping it in an arch VGPR (defeats AGPR parking). Zero instructions.
#define PF4(v) asm("" : "+v"((v).x), "+v"((v).y), "+v"((v).z), "+v"((v).w))
#define PF1(v) asm("" : "+v"(v))

// ---------------- Layer 1: bidirectional, input dim 4 ----------------
// r8 structure + per-iter pins + 8-step-batched out1 stores (amortize the
// pre-barrier vmcnt(0) store drain from every step to 1-in-8).
__global__ __launch_bounds__(256, 2)
void lstm_layer1(const float* __restrict__ x,
                 const float* __restrict__ Wih_f, const float* __restrict__ Whh_f, const float* __restrict__ b_f,
                 const float* __restrict__ Wih_b, const float* __restrict__ Whh_b, const float* __restrict__ b_b,
                 float* __restrict__ out1)
{
    const int bidx = blockIdx.x >> 1;
    const int dir  = blockIdx.x & 1;
    const float* __restrict__ Wih = dir ? Wih_b : Wih_f;
    const float* __restrict__ Whh = dir ? Whh_b : Whh_f;
    const float* __restrict__ bb  = dir ? b_b   : b_f;

    const int tid = threadIdx.x;
    const int u   = tid >> 2;
    const int p   = tid & 3;

    __shared__ float xlds[TLEN * 4];
    __shared__ float hbuf[2][HDIM];

    {
        const float4* src = (const float4*)(x + (size_t)bidx * TLEN * 4);
        float4* dst = (float4*)xlds;
        #pragma unroll
        for (int i = 0; i < 8; ++i) dst[tid + 256 * i] = src[tid + 256 * i];
    }
    if (tid < 2 * HDIM) ((float*)hbuf)[tid] = 0.f;

    const float* wbase = Whh + (size_t)u * HDIM + 16 * p;
    float4 W00 = *(const float4*)(wbase + 0*4096 +  0), W01 = *(const float4*)(wbase + 0*4096 +  4),
           W02 = *(const float4*)(wbase + 0*4096 +  8), W03 = *(const float4*)(wbase + 0*4096 + 12);
    float4 W10 = *(const float4*)(wbase + 1*4096 +  0), W11 = *(const float4*)(wbase + 1*4096 +  4),
           W12 = *(const float4*)(wbase + 1*4096 +  8), W13 = *(const float4*)(wbase + 1*4096 + 12);
    float4 W20 = *(const float4*)(wbase + 2*4096 +  0), W21 = *(const float4*)(wbase + 2*4096 +  4),
           W22 = *(const float4*)(wbase + 2*4096 +  8), W23 = *(const float4*)(wbase + 2*4096 + 12);
    float4 W30 = *(const float4*)(wbase + 3*4096 +  0), W31 = *(const float4*)(wbase + 3*4096 +  4),
           W32 = *(const float4*)(wbase + 3*4096 +  8), W33 = *(const float4*)(wbase + 3*4096 + 12);
    float4 I0 = *(const float4*)(Wih + (0*64 + u) * 4);
    float4 I1 = *(const float4*)(Wih + (1*64 + u) * 4);
    float4 I2 = *(const float4*)(Wih + (2*64 + u) * 4);
    float4 I3 = *(const float4*)(Wih + (3*64 + u) * 4);
    float b0 = bb[u], b1 = bb[64 + u], b2g = bb[128 + u], b3 = bb[192 + u];
    __syncthreads();

    float c = 0.f;
    const float* xp = xlds + (dir ? (TLEN - 1) * 4 : 0);
    const int xstep = dir ? -4 : 4;
    float* ob = out1 + (size_t)bidx * TLEN * (2 * HDIM)
              + (size_t)(dir ? (TLEN - 1) : 0) * (2 * HDIM) + dir * HDIM + u;
    const ptrdiff_t ostep = dir ? -(2 * HDIM) : (2 * HDIM);

    for (int so = 0; so < TLEN; so += 8) {
        float hh[8];
        #pragma unroll
        for (int si = 0; si < 8; ++si) {
            PF4(W00); PF4(W01); PF4(W02); PF4(W03);
            PF4(W10); PF4(W11); PF4(W12); PF4(W13);
            PF4(W20); PF4(W21); PF4(W22); PF4(W23);
            PF4(W30); PF4(W31); PF4(W32); PF4(W33);
            PF4(I0); PF4(I1); PF4(I2); PF4(I3);
            PF1(b0); PF1(b1); PF1(b2g); PF1(b3);

            const float* hb = hbuf[si & 1];
            const float4 h0 = *(const float4*)(hb + 16 * p + 0);
            const float4 h1 = *(const float4*)(hb + 16 * p + 4);
            const float4 h2 = *(const float4*)(hb + 16 * p + 8);
            const float4 h3 = *(const float4*)(hb + 16 * p + 12);

            v2f a0 = {0.f, 0.f}, a1 = {0.f, 0.f}, a2 = {0.f, 0.f}, a3 = {0.f, 0.f};
            pk4(a0, W00, h0); pk4(a0, W01, h1); pk4(a0, W02, h2); pk4(a0, W03, h3);
            pk4(a1, W10, h0); pk4(a1, W11, h1); pk4(a1, W12, h2); pk4(a1, W13, h3);
            pk4(a2, W20, h0); pk4(a2, W21, h1); pk4(a2, W22, h2); pk4(a2, W23, h3);
            pk4(a3, W30, h0); pk4(a3, W31, h1); pk4(a3, W32, h2); pk4(a3, W33, h3);
            float g0 = a0.x + a0.y, g1 = a1.x + a1.y, g2 = a2.x + a2.y, g3 = a3.x + a3.y;

            g0 = dpp_xor2_add(dpp_xor1_add(g0));
            g1 = dpp_xor2_add(dpp_xor1_add(g1));
            g2 = dpp_xor2_add(dpp_xor1_add(g2));
            g3 = dpp_xor2_add(dpp_xor1_add(g3));

            const float4 xv = *(const float4*)(xp + si * xstep);
            v2f e0 = {g0 + b0, 0.f}, e1 = {g1 + b1, 0.f}, e2 = {g2 + b2g, 0.f}, e3 = {g3 + b3, 0.f};
            pk4(e0, I0, xv); pk4(e1, I1, xv); pk4(e2, I2, xv); pk4(e3, I3, xv);
            g0 = e0.x + e0.y; g1 = e1.x + e1.y; g2 = e2.x + e2.y; g3 = e3.x + e3.y;

            const float ig = sigmoid_fast(g0);
            const float fg = sigmoid_fast(g1);
            const float gg = tanh_fast(g2);
            const float og = sigmoid_fast(g3);
            c = fmaf(fg, c, ig * gg);
            const float h = og * tanh_fast(c);

            if (p == 0) hbuf[(si & 1) ^ 1][u] = h;
            hh[si] = h;
            __syncthreads();
        }
        if (p == 0) {
            #pragma unroll
            for (int j = 0; j < 8; ++j) ob[j * ostep] = hh[j];
        }
        ob += 8 * ostep;
        xp += 8 * xstep;
    }
}

// ---------------- pre-GEMM: pre[b,t,4H] = Wih2 @ out1[b,t] + b2 -------------
// grid = B * (T/GTS), 256 threads; thread owns output row r (gate*64+u).
__global__ __launch_bounds__(256, 2)
void pre_gemm(const float* __restrict__ out1, const float* __restrict__ Wih2,
              const float* __restrict__ b2, float* __restrict__ pre)
{
    const int b  = blockIdx.x >> 6;          // T/GTS = 64
    const int tc = blockIdx.x & 63;
    const int t0 = tc * GTS;
    const int r  = threadIdx.x;

    __shared__ float xin[GTS][2 * HDIM];     // 16 KB

    const float4* s4 = (const float4*)(out1 + ((size_t)b * TLEN + t0) * (2 * HDIM));
    #pragma unroll
    for (int i = 0; i < 4; ++i) ((float4*)xin)[r + 256 * i] = s4[r + 256 * i];

    float4 wr[32];
    const float4* w4 = (const float4*)(Wih2 + (size_t)r * (2 * HDIM));
    #pragma unroll
    for (int i = 0; i < 32; ++i) wr[i] = w4[i];
    const float bias = b2[r];
    __syncthreads();

    float* dst = pre + ((size_t)b * TLEN + t0) * 256 + r;
    for (int t = 0; t < GTS; ++t) {
        #pragma unroll
        for (int i = 0; i < 32; ++i) PF4(wr[i]);
        v2f acc = {0.f, 0.f};
        const float4* xv = (const float4*)xin[t];
        #pragma unroll
        for (int i = 0; i < 32; ++i) pk4(acc, wr[i], xv[i]);
        dst[(size_t)t * 256] = bias + acc.x + acc.y;
    }
}

// ---------------- Layer 2 (slim): h-dot only + pre-add + FC ----------------
// grid = BATCH, 256 threads. Quad owns unit u = tid>>2; lane p owns h-slice
// [16p,16p+16). 64 weight floats/lane, quad-DPP reduce only (no swizzle).
__global__ __launch_bounds__(256, 1)
void lstm_layer2(const float* __restrict__ pre, const float* __restrict__ Whh2,
                 const float* __restrict__ Wfc, const float* __restrict__ bfc,
                 float* __restrict__ out)
{
    const int bidx = blockIdx.x;
    const int tid  = threadIdx.x;
    const int u    = tid >> 2;
    const int p    = tid & 3;

    __shared__ float prebuf[2][CH][256];   // 32 KB
    __shared__ float hbuf[2][HDIM];

    const float* wbase = Whh2 + (size_t)u * HDIM + 16 * p;
    float4 H00 = *(const float4*)(wbase + 0*4096 +  0), H01 = *(const float4*)(wbase + 0*4096 +  4),
           H02 = *(const float4*)(wbase + 0*4096 +  8), H03 = *(const float4*)(wbase + 0*4096 + 12);
    float4 H10 = *(const float4*)(wbase + 1*4096 +  0), H11 = *(const float4*)(wbase + 1*4096 +  4),
           H12 = *(const float4*)(wbase + 1*4096 +  8), H13 = *(const float4*)(wbase + 1*4096 + 12);
    float4 H20 = *(const float4*)(wbase + 2*4096 +  0), H21 = *(const float4*)(wbase + 2*4096 +  4),
           H22 = *(const float4*)(wbase + 2*4096 +  8), H23 = *(const float4*)(wbase + 2*4096 + 12);
    float4 H30 = *(const float4*)(wbase + 3*4096 +  0), H31 = *(const float4*)(wbase + 3*4096 +  4),
           H32 = *(const float4*)(wbase + 3*4096 +  8), H33 = *(const float4*)(wbase + 3*4096 + 12);

    if (tid < 2 * HDIM) ((float*)hbuf)[tid] = 0.f;

    const float4* src = (const float4*)(pre + (size_t)bidx * TLEN * 256);
    #pragma unroll
    for (int i = 0; i < 4; ++i) ((float4*)&prebuf[0][0][0])[tid + 256 * i] = src[tid + 256 * i];
    __syncthreads();

    float c = 0.f;

    for (int chunk = 0; chunk < TLEN / CH; ++chunk) {
        const int cb = chunk & 1;
        const bool havenext = (chunk + 1 < TLEN / CH);
        float4 pf0, pf1, pf2, pf3;
        if (havenext) {
            const float4* s2 = src + (size_t)(chunk + 1) * (CH * 64);
            pf0 = s2[tid]; pf1 = s2[tid + 256]; pf2 = s2[tid + 512]; pf3 = s2[tid + 768];
        }
        #pragma unroll 2
        for (int ts = 0; ts < CH; ++ts) {
            PF4(H00); PF4(H01); PF4(H02); PF4(H03);
            PF4(H10); PF4(H11); PF4(H12); PF4(H13);
            PF4(H20); PF4(H21); PF4(H22); PF4(H23);
            PF4(H30); PF4(H31); PF4(H32); PF4(H33);

            const float* hb = hbuf[ts & 1];
            const float4 h0 = *(const float4*)(hb + 16 * p + 0);
            const float4 h1 = *(const float4*)(hb + 16 * p + 4);
            const float4 h2 = *(const float4*)(hb + 16 * p + 8);
            const float4 h3 = *(const float4*)(hb + 16 * p + 12);

            // gate preactivation contributions from pre (independent of h;
            // issue early so latency hides under the dot chain)
            const float* pr = &prebuf[cb][ts][0];
            const float q0 = pr[0 * 64 + u];
            const float q1 = pr[1 * 64 + u];
            const float q2 = pr[2 * 64 + u];
            const float q3 = pr[3 * 64 + u];

            v2f a0 = {0.f, 0.f}, a1 = {0.f, 0.f}, a2 = {0.f, 0.f}, a3 = {0.f, 0.f};
            pk4(a0, H00, h0); pk4(a0, H01, h1); pk4(a0, H02, h2); pk4(a0, H03, h3);
            pk4(a1, H10, h0); pk4(a1, H11, h1); pk4(a1, H12, h2); pk4(a1, H13, h3);
            pk4(a2, H20, h0); pk4(a2, H21, h1); pk4(a2, H22, h2); pk4(a2, H23, h3);
            pk4(a3, H30, h0); pk4(a3, H31, h1); pk4(a3, H32, h2); pk4(a3, H33, h3);
            float g0 = a0.x + a0.y, g1 = a1.x + a1.y, g2 = a2.x + a2.y, g3 = a3.x + a3.y;

            g0 = dpp_xor2_add(dpp_xor1_add(g0)) + q0;
            g1 = dpp_xor2_add(dpp_xor1_add(g1)) + q1;
            g2 = dpp_xor2_add(dpp_xor1_add(g2)) + q2;
            g3 = dpp_xor2_add(dpp_xor1_add(g3)) + q3;

            const float ig = sigmoid_fast(g0);
            const float fg = sigmoid_fast(g1);
            const float gg = tanh_fast(g2);
            const float og = sigmoid_fast(g3);
            c = fmaf(fg, c, ig * gg);
            const float h = og * tanh_fast(c);

            if (p == 0) hbuf[(ts & 1) ^ 1][u] = h;
            __syncthreads();
        }
        if (havenext) {
            float4* d4 = (float4*)&prebuf[cb ^ 1][0][0];
            d4[tid] = pf0; d4[tid + 256] = pf1; d4[tid + 512] = pf2; d4[tid + 768] = pf3;
            __syncthreads();
        }
    }

    if (tid < 64) {
        float part = hbuf[0][tid] * Wfc[tid];
        #pragma unroll
        for (int m = 1; m < 64; m <<= 1) part += __shfl_xor(part, m, 64);
        if (tid == 0) out[bidx] = part + bfc[0];
    }
}

// ---------------- Fallback layer 2 (r8-proven, reads out1 directly) --------
__global__ __launch_bounds__(512, 2)
void lstm_layer2_fb(const float* __restrict__ out1,
                    const float* __restrict__ Wih2, const float* __restrict__ Whh2, const float* __restrict__ bias2,
                    const float* __restrict__ Wfc, const float* __restrict__ bfc,
                    float* __restrict__ out)
{
    const int bidx = blockIdx.x;
    const int tid  = threadIdx.x;
    const int w    = tid >> 6;
    const int lane = tid & 63;
    const int ul   = lane >> 3;
    const int p8   = lane & 7;
    const int u    = w * 8 + ul;
    const int rot  = p8 >> 1;

    __shared__ float inbuf[2][CH][2 * HDIM];
    __shared__ float hbuf[2][HDIM];

    const float* whbase = Whh2 + (size_t)u * HDIM + 8 * p8;
    const float4 H00 = *(const float4*)(whbase + 0*4096 + 0), H01 = *(const float4*)(whbase + 0*4096 + 4);
    const float4 H10 = *(const float4*)(whbase + 1*4096 + 0), H11 = *(const float4*)(whbase + 1*4096 + 4);
    const float4 H20 = *(const float4*)(whbase + 2*4096 + 0), H21 = *(const float4*)(whbase + 2*4096 + 4);
    const float4 H30 = *(const float4*)(whbase + 3*4096 + 0), H31 = *(const float4*)(whbase + 3*4096 + 4);
    const float* wibase = Wih2 + (size_t)u * 128 + 16 * p8;
    #define LWI(g, j) *(const float4*)(wibase + (g)*8192 + ((((j) + rot) & 3) << 2))
    const float4 X00 = LWI(0,0), X01 = LWI(0,1), X02 = LWI(0,2), X03 = LWI(0,3);
    const float4 X10 = LWI(1,0), X11 = LWI(1,1), X12 = LWI(1,2), X13 = LWI(1,3);
    const float4 X20 = LWI(2,0), X21 = LWI(2,1), X22 = LWI(2,2), X23 = LWI(2,3);
    const float4 X30 = LWI(3,0), X31 = LWI(3,1), X32 = LWI(3,2), X33 = LWI(3,3);
    #undef LWI
    const float b0 = bias2[u], b1 = bias2[64 + u], b2g = bias2[128 + u], b3 = bias2[192 + u];

    if (tid < 2 * HDIM) ((float*)hbuf)[tid] = 0.f;

    const float4* src = (const float4*)(out1 + (size_t)bidx * TLEN * (2 * HDIM));
    ((float4*)&inbuf[0][0][0])[tid] = src[tid];
    __syncthreads();

    float c = 0.f;

    for (int chunk = 0; chunk < TLEN / CH; ++chunk) {
        const int cb = chunk & 1;
        const bool havenext = (chunk + 1 < TLEN / CH);
        float4 pf;
        if (havenext) pf = src[(size_t)(chunk + 1) * 512 + tid];

        #pragma unroll 2
        for (int ts = 0; ts < CH; ++ts) {
            const float* hb = hbuf[(chunk * CH + ts) & 1];
            const float* xr = &inbuf[cb][ts][16 * p8];

            const float4 x0 = *(const float4*)(xr + (((0 + rot) & 3) << 2));
            const float4 x1 = *(const float4*)(xr + (((1 + rot) & 3) << 2));
            const float4 x2 = *(const float4*)(xr + (((2 + rot) & 3) << 2));
            const float4 x3 = *(const float4*)(xr + (((3 + rot) & 3) << 2));
            const float4 h0 = *(const float4*)(hb + 8 * p8 + 0);
            const float4 h1 = *(const float4*)(hb + 8 * p8 + 4);

            v2f a0 = {0.f,0.f}, a1 = {0.f,0.f}, a2 = {0.f,0.f}, a3 = {0.f,0.f};
            pk4(a0, X00, x0); pk4(a0, X01, x1); pk4(a0, X02, x2); pk4(a0, X03, x3);
            pk4(a0, H00, h0); pk4(a0, H01, h1);
            pk4(a1, X10, x0); pk4(a1, X11, x1); pk4(a1, X12, x2); pk4(a1, X13, x3);
            pk4(a1, H10, h0); pk4(a1, H11, h1);
            pk4(a2, X20, x0); pk4(a2, X21, x1); pk4(a2, X22, x2); pk4(a2, X23, x3);
            pk4(a2, H20, h0); pk4(a2, H21, h1);
            pk4(a3, X30, x0); pk4(a3, X31, x1); pk4(a3, X32, x2); pk4(a3, X33, x3);
            pk4(a3, H30, h0); pk4(a3, H31, h1);
            float g0 = a0.x + a0.y, g1 = a1.x + a1.y, g2 = a2.x + a2.y, g3 = a3.x + a3.y;

            g0 = swz_xor4_add(dpp_xor2_add(dpp_xor1_add(g0))) + b0;
            g1 = swz_xor4_add(dpp_xor2_add(dpp_xor1_add(g1))) + b1;
            g2 = swz_xor4_add(dpp_xor2_add(dpp_xor1_add(g2))) + b2g;
            g3 = swz_xor4_add(dpp_xor2_add(dpp_xor1_add(g3))) + b3;

            const float ig = sigmoid_fast(g0);
            const float fg = sigmoid_fast(g1);
            const float gg = tanh_fast(g2);
            const float og = sigmoid_fast(g3);
            c = fmaf(fg, c, ig * gg);
            const float h = og * tanh_fast(c);

            if (p8 == 0) hbuf[((chunk * CH + ts) & 1) ^ 1][u] = h;
            __syncthreads();
        }
        if (havenext) {
            ((float4*)&inbuf[cb ^ 1][0][0])[tid] = pf;
            __syncthreads();
        }
    }

    if (w == 0) {
        float part = hbuf[0][lane] * Wfc[lane];
        #pragma unroll
        for (int m = 1; m < 64; m <<= 1) part += __shfl_xor(part, m, 64);
        if (lane == 0) out[bidx] = part + bfc[0];
    }
}

extern "C" void kernel_launch(void* const* d_in, const int* in_sizes, int n_in,
                              void* d_out, int out_size, void* d_ws, size_t ws_size,
                              hipStream_t stream) {
    const float* x     = (const float*)d_in[0];
    const float* Wih_f = (const float*)d_in[1];
    const float* Whh_f = (const float*)d_in[2];
    const float* b_f   = (const float*)d_in[3];
    const float* Wih_b = (const float*)d_in[4];
    const float* Whh_b = (const float*)d_in[5];
    const float* b_b   = (const float*)d_in[6];
    const float* Wih2  = (const float*)d_in[7];
    const float* Whh2  = (const float*)d_in[8];
    const float* b2    = (const float*)d_in[9];
    const float* Wfc   = (const float*)d_in[10];
    const float* bfc   = (const float*)d_in[11];

    const size_t out1_bytes = (size_t)BATCH * TLEN * 128 * 4;   // 268 MB
    const size_t pre_bytes  = (size_t)BATCH * TLEN * 256 * 4;   // 537 MB
    float* out1 = (float*)d_ws;

    lstm_layer1<<<dim3(2 * BATCH), dim3(256), 0, stream>>>(
        x, Wih_f, Whh_f, b_f, Wih_b, Whh_b, b_b, out1);

    if (ws_size >= out1_bytes + pre_bytes) {
        float* pre = (float*)((char*)d_ws + out1_bytes);
        pre_gemm<<<dim3(BATCH * (TLEN / GTS)), dim3(256), 0, stream>>>(
            out1, Wih2, b2, pre);
        lstm_layer2<<<dim3(BATCH), dim3(256), 0, stream>>>(
            pre, Whh2, Wfc, bfc, (float*)d_out);
    } else {
        lstm_layer2_fb<<<dim3(BATCH), dim3(512), 0, stream>>>(
            out1, Wih2, Whh2, b2, Wfc, bfc, (float*)d_out);
    }
}